// Round 1
// baseline (258.012 us; speedup 1.0000x reference)
//
#include <hip/hip_runtime.h>

#define RS2f 0.70710678118654752f

// DPP quad_perm encodings: sel0 | sel1<<2 | sel2<<4 | sel3<<6
#define QP_XOR1 0xB1   // [1,0,3,2]
#define QP_XOR2 0x4E   // [2,3,0,1]
#define QP_BC0  0x00
#define QP_BC1  0x55
#define QP_BC2  0xAA
#define QP_BC3  0xFF

typedef float v2f __attribute__((ext_vector_type(2)));

template<int CTRL> __device__ __forceinline__ float dppf(float x) {
  return __int_as_float(__builtin_amdgcn_update_dpp(
      0, __float_as_int(x), CTRL, 0xF, 0xF, true));
}
template<int CTRL> __device__ __forceinline__ v2f dpp2(v2f v) {
  v2f r; r.x = dppf<CTRL>(v.x); r.y = dppf<CTRL>(v.y); return r;
}

// cross-quad exchange lane ^ 4 (ds_swizzle BitMode: xor=4, and=0x1F, or=0)
__device__ __forceinline__ float swz4(float x) {
  return __int_as_float(__builtin_amdgcn_ds_swizzle(__float_as_int(x), 0x101F));
}
__device__ __forceinline__ v2f swz4v(v2f v) {
  v2f r; r.x = swz4(v.x); r.y = swz4(v.y); return r;
}

__device__ __forceinline__ float sxor(float x, int sm) {
  return __int_as_float(__float_as_int(x) ^ sm);
}
__device__ __forceinline__ v2f vsplat(float a) { v2f r; r.x = a; r.y = a; return r; }
__device__ __forceinline__ v2f vperp(v2f v) { v2f r; r.x = -v.y; r.y = v.x; return r; }  //  i*v
__device__ __forceinline__ v2f vperc(v2f v) { v2f r; r.x = v.y; r.y = -v.x; return r; }  // -i*v
__device__ __forceinline__ v2f vfma2(float a, v2f b, v2f c) {
  return __builtin_elementwise_fma(vsplat(a), b, c);
}
__device__ __forceinline__ v2f vmul2(float a, v2f b) { return vsplat(a) * b; }

// Closed-form row0 of U = RZ(a4)RY(a3)RZ(a2)RY(a1)RZ(a0)·H  (verified r8).
__device__ __forceinline__ void build_gate(float a0, float a1, float a2, float a3, float a4,
                                           float &w0r, float &w0i, float &w1r, float &w1i) {
  float sBp, cBp, sBm, cBm, sC, cC, sP, cP, sM, cM;
  __sincosf(0.5f * (a1 + a3), &sBp, &cBp);
  __sincosf(0.5f * (a1 - a3), &sBm, &cBm);
  __sincosf(0.5f * a2,        &sC,  &cC);
  __sincosf(0.5f * (a0 + a4), &sP,  &cP);
  __sincosf(0.5f * (a0 - a4), &sM,  &cM);
  float m00r =  cBp * cC, m00i = -cBm * sC;
  float m01r = -sBp * cC, m01i =  sBm * sC;
  float alr = fmaf(m00r, cP,  m00i * sP);
  float ali = fmaf(m00i, cP, -m00r * sP);
  float ber = fmaf(m01r, cM, -m01i * sM);
  float bei = fmaf(m01i, cM,  m01r * sM);
  w0r = RS2f * (alr + ber); w0i = RS2f * (ali + bei);
  w1r = RS2f * (alr - ber); w1i = RS2f * (ali - bei);
}

// Lane-q (q = tid&3) builds the gate for qubit q. Both half-groups (h=0/1)
// execute the identical stream, so per-wave cost is unchanged vs 4-lane layout.
#define PICK_FULL                                                            \
  a0 = l0 ? P[0][0] : l1 ? P[1][1] : l2 ? P[2][2] : P[3][3];                 \
  a1 = l0 ? P[0][1] : l1 ? P[1][2] : l2 ? P[2][3] : 0.f;                     \
  a2 = l0 ? P[0][2] : l1 ? P[1][3] : l2 ? P[3][0] : 0.f;                     \
  a3 = l0 ? P[0][3] : l1 ? P[2][0] : l2 ? P[3][1] : 0.f;                     \
  a4 = l0 ? P[1][0] : l1 ? P[2][1] : l2 ? P[3][2] : 0.f;

#define PICK_W2                                                              \
  a0 = l0 ? P[0][0] : l1 ? P[2][1] : 0.f;                                    \
  a1 = l0 ? P[0][1] : l1 ? P[3][0] : 0.f;                                    \
  a2 = l0 ? P[1][0] : l1 ? P[3][1] : 0.f;                                    \
  a3 = l0 ? P[1][1] : 0.f;                                                   \
  a4 = l0 ? P[2][0] : 0.f;

#define PICK_H2                                                              \
  a0 = l0 ? P[0][0] : l1 ? P[1][1] : 0.f;                                    \
  a1 = l0 ? P[0][1] : l1 ? P[1][2] : 0.f;                                    \
  a2 = l0 ? P[0][2] : l1 ? P[1][3] : 0.f;                                    \
  a3 = l0 ? P[0][3] : 0.f;                                                   \
  a4 = l0 ? P[1][0] : 0.f;

#define PICK_22                                                              \
  a0 = l0 ? P[0][0] : 0.f;                                                   \
  a1 = l0 ? P[0][1] : 0.f;                                                   \
  a2 = l0 ? P[1][0] : 0.f;                                                   \
  a3 = l0 ? P[1][1] : 0.f;                                                   \
  a4 = 0.f;

// 8-lane state layout: amp n = h*8 + (q>>1)*4 + (q&1)*2 + m; s[m] = (re,im).
// qubit0 (MSB) ~ h (lane^4, ds_swizzle); qubit1 ~ q&2 (lane^2, DPP XOR2);
// qubit2 ~ q&1 (lane^1, DPP XOR1); qubit3 (LSB) ~ m (intra-lane).
// Row1 of each SU(2)-with-H gate: [conj(w1), -conj(w0)] (same algebra as 4-lane version).
#define APPLY_Z do {                                                         \
  { float w0r = dppf<QP_BC0>(Wc0), w0i = dppf<QP_BC0>(Wc1);                  \
    float w1r = dppf<QP_BC0>(Wc2), w1i = dppf<QP_BC0>(Wc3);                  \
    float uar = sxor(w0r, smH), uai = w0i;                                   \
    float ubr = w1r,            ubi = sxor(w1i, smH);                        \
    _Pragma("unroll")                                                        \
    for (int m = 0; m < 2; ++m) {                                            \
      v2f p = swz4v(s[m]);                                                   \
      v2f a = s[m];                                                          \
      s[m] = vfma2(uar, a, vfma2(uai, vperp(a),                              \
                   vfma2(ubr, p, vmul2(ubi, vperp(p)))));                    \
    } }                                                                      \
  { float w0r = dppf<QP_BC1>(Wc0), w0i = dppf<QP_BC1>(Wc1);                  \
    float w1r = dppf<QP_BC1>(Wc2), w1i = dppf<QP_BC1>(Wc3);                  \
    float uar = sxor(w0r, sm2), uai = w0i;                                   \
    float ubr = w1r,            ubi = sxor(w1i, sm2);                        \
    _Pragma("unroll")                                                        \
    for (int m = 0; m < 2; ++m) {                                            \
      v2f p = dpp2<QP_XOR2>(s[m]);                                           \
      v2f a = s[m];                                                          \
      s[m] = vfma2(uar, a, vfma2(uai, vperp(a),                              \
                   vfma2(ubr, p, vmul2(ubi, vperp(p)))));                    \
    } }                                                                      \
  { float w0r = dppf<QP_BC2>(Wc0), w0i = dppf<QP_BC2>(Wc1);                  \
    float w1r = dppf<QP_BC2>(Wc2), w1i = dppf<QP_BC2>(Wc3);                  \
    float uar = sxor(w0r, sm1), uai = w0i;                                   \
    float ubr = w1r,            ubi = sxor(w1i, sm1);                        \
    _Pragma("unroll")                                                        \
    for (int m = 0; m < 2; ++m) {                                            \
      v2f p = dpp2<QP_XOR1>(s[m]);                                           \
      v2f a = s[m];                                                          \
      s[m] = vfma2(uar, a, vfma2(uai, vperp(a),                              \
                   vfma2(ubr, p, vmul2(ubi, vperp(p)))));                    \
    } }                                                                      \
  { float w0r = dppf<QP_BC3>(Wc0), w0i = dppf<QP_BC3>(Wc1);                  \
    float w1r = dppf<QP_BC3>(Wc2), w1i = dppf<QP_BC3>(Wc3);                  \
    float nw0r = -w0r, nw0i = -w0i;                                          \
    v2f lo = s[0], hi = s[1];                                                \
    s[0] = vfma2(w0r, lo, vfma2(w0i, vperp(lo),                              \
                 vfma2(w1r, hi, vmul2(w1i, vperp(hi)))));                    \
    s[1] = vfma2(w1r, lo, vfma2(w1i, vperc(lo),                              \
                 vfma2(nw0r, hi, vmul2(nw0i, vperc(hi))))); }                \
  s[0] = vfma2(czk0, s[0], vmul2(szk0, vperp(s[0])));                        \
  s[1] = vfma2(czk1, s[1], vmul2(szk1, vperp(s[1])));                        \
  _Pragma("unroll")                                                          \
  for (int m = 0; m < 2; ++m) {                                              \
    v2f p = swz4v(s[m]);                                                     \
    s[m] = vfma2(cry, s[m], vmul2(sgn0, p));                                 \
  }                                                                          \
  _Pragma("unroll")                                                          \
  for (int m = 0; m < 2; ++m) {                                              \
    v2f p = dpp2<QP_XOR2>(s[m]);                                             \
    s[m] = vfma2(cry, s[m], vmul2(sgn1, p));                                 \
  }                                                                          \
  _Pragma("unroll")                                                          \
  for (int m = 0; m < 2; ++m) {                                              \
    v2f p = dpp2<QP_XOR1>(s[m]);                                             \
    s[m] = vfma2(cry, s[m], vmul2(sgn2, p));                                 \
  }                                                                          \
  { v2f lo = s[0], hi = s[1];                                                \
    s[0] = vfma2(cry, lo, vmul2(nsry, hi));                                  \
    s[1] = vfma2(sry, lo, vmul2(cry, hi)); }                                 \
  { v2f q0 = s[0]*s[0], q1 = s[1]*s[1];                                      \
    float p0 = q0.x + q0.y, p1 = q1.x + q1.y;                                \
    float t_ = p0 + p1;                                                      \
    np0 = sxor(t_, smH);                                                     \
    np1 = sxor(t_, sm2);                                                     \
    np2 = sxor(t_, sm1);                                                     \
    np3 = p0 - p1;                                                           \
  }                                                                          \
} while (0)

// Deferred readout: quad butterfly, one cross-quad exchange delivering only
// the 2 features this half-group folds (h=0 -> o0,o1; h=1 -> o2,o3),
// then a 5x2 fc1 fold (float2 weight reads).
#define BF_FOLD do {                                                         \
  float o0 = pd0, o1 = pd1, o2 = pd2, o3 = pd3;                              \
  o0 += dppf<QP_XOR1>(o0); o0 += dppf<QP_XOR2>(o0);                          \
  o1 += dppf<QP_XOR1>(o1); o1 += dppf<QP_XOR2>(o1);                          \
  o2 += dppf<QP_XOR1>(o2); o2 += dppf<QP_XOR2>(o2);                          \
  o3 += dppf<QP_XOR1>(o3); o3 += dppf<QP_XOR2>(o3);                          \
  float uA = hsel ? o0 : o2;   /* what our cross-quad partner needs */       \
  float uB = hsel ? o1 : o3;                                                 \
  float fa = (hsel ? o2 : o0) + swz4(uA);                                    \
  float fb = (hsel ? o3 : o1) + swz4(uB);                                    \
  const float* wp = swl + pdWin * 4;                                         \
  float2 wv0 = *(const float2*)(wp);                                         \
  float2 wv1 = *(const float2*)(wp + 784);                                   \
  float2 wv2 = *(const float2*)(wp + 1568);                                  \
  float2 wv3 = *(const float2*)(wp + 2352);                                  \
  float2 wv4 = *(const float2*)(wp + 3136);                                  \
  h1[0] = fmaf(wv0.x, fa, fmaf(wv0.y, fb, h1[0]));                           \
  h1[1] = fmaf(wv1.x, fa, fmaf(wv1.y, fb, h1[1]));                           \
  h1[2] = fmaf(wv2.x, fa, fmaf(wv2.y, fb, h1[2]));                           \
  h1[3] = fmaf(wv3.x, fa, fmaf(wv3.y, fb, h1[3]));                           \
  h1[4] = fmaf(wv4.x, fa, fmaf(wv4.y, fb, h1[4]));                           \
} while (0)

#define SHIFT_PEND(WIN)  pd0 = np0; pd1 = np1; pd2 = np2; pd3 = np3; pdWin = (WIN);
#define ROTATE_W  Wc0 = Wn0; Wc1 = Wn1; Wc2 = Wn2; Wc3 = Wn3;

__global__ void __launch_bounds__(256)
quanv_kernel(const float* __restrict__ x,
             const float* __restrict__ crz_t,
             const float* __restrict__ ry_t,
             const float* __restrict__ fc1_w,
             const float* __restrict__ fc1_b,
             const float* __restrict__ fc2_w,
             const float* __restrict__ fc2_b,
             float* __restrict__ out, int B)
{
  __shared__ float sw[20 * 784];
  const int tid = threadIdx.x;
  for (int i = tid; i < (20 * 784) / 4; i += 256)
    ((float4*)sw)[i] = ((const float4*)fc1_w)[i];
  __syncthreads();

  const int l8   = tid & 7;        // lane within 8-lane group
  const int q    = l8 & 3;         // quad lane (gate-builder qubit id)
  const int hsel = l8 >> 2;        // cross-quad half (qubit0 bit)
  const int b = (blockIdx.x * 256 + tid) >> 3; // image id
  if (b >= B) return;
  const float* img = x + (size_t)b * 784;
  const bool l0 = (q == 0), l1 = (q == 1), l2 = (q == 2);

  // ---- uniform scalar-derived constants ----
  const float theta = crz_t[0];
  const float ryt   = ry_t[0];
  float cry, sry;
  __sincosf(0.5f * ryt, &sry, &cry);
  const float nsry = -sry;
  const float sgn0 = hsel    ? sry : -sry;   // qubit0 (lane^4)
  const float sgn1 = (q & 2) ? sry : -sry;   // qubit1 (lane^2)
  const float sgn2 = (q & 1) ? sry : -sry;   // qubit2 (lane^1)
  const int SBIT = (int)0x80000000;
  const int smH = hsel    ? SBIT : 0;
  const int sm2 = (q & 2) ? SBIT : 0;
  const int sm1 = (q & 1) ? SBIT : 0;

  // CRZ diag signs for this lane's two amps (n = 8h+4(q>>1)+2(q&1)+m):
  // g(n) = B0(2B1-1) + B1(2B2-1) + B2(2B3-1) + B3(2B0-1)
  const int B1b = (q >> 1) & 1, B2b = q & 1;
  const int gb = hsel * (2 * B1b - 1) + B1b * (2 * B2b - 1);
  const float g0f = (float)(gb - B2b);
  const float g1f = (float)(gb + B2b + 2 * hsel - 1);
  float czk0, szk0, czk1, szk1;
  __sincosf(0.5f * theta * g0f, &szk0, &czk0);
  __sincosf(0.5f * theta * g1f, &szk1, &czk1);

  // state: 2 amps per lane
  v2f s[2];
  s[0].x = 0.f; s[0].y = 0.f; s[1].x = 0.f; s[1].y = 0.f;
  if (l8 == 0) s[0].x = 1.f;

  float h1[5];
#pragma unroll
  for (int j = 0; j < 5; ++j) h1[j] = 0.f;
  // rows 5q..5q+4; feature columns win*4 + 2h + {0,1}
  const float* swl = sw + 5 * q * 784 + 2 * hsel;

  float P[4][4];
  float a0, a1, a2, a3, a4;
  float Wc0, Wc1, Wc2, Wc3, Wn0, Wn1, Wn2, Wn3;
  float np0, np1, np2, np3;
  float pd0 = 0.f, pd1 = 0.f, pd2 = 0.f, pd3 = 0.f;  // pending readout (0-seeded)
  int pdWin = 0;

  // ================= main rows: wi = 0..12 (h = 4 always) =================
#pragma unroll 1
  for (int wi = 0; wi < 13; ++wi) {
    const float* imgw = img + (2 * wi) * 28;

    // peel wj = 0: fresh load + build only (prev row's pending carries over)
#pragma unroll
    for (int r = 0; r < 4; ++r) {
      float4 v = *(const float4*)(imgw + r * 28);
      P[r][0]=v.x; P[r][1]=v.y; P[r][2]=v.z; P[r][3]=v.w;
    }
    PICK_FULL;
    build_gate(a0, a1, a2, a3, a4, Wc0, Wc1, Wc2, Wc3);

    // prefetch window 1's new columns (cols 4,5)
    float2 Q0 = *(const float2*)(imgw + 0 * 28 + 4);
    float2 Q1 = *(const float2*)(imgw + 1 * 28 + 4);
    float2 Q2 = *(const float2*)(imgw + 2 * 28 + 4);
    float2 Q3 = *(const float2*)(imgw + 3 * 28 + 4);

    // hot loop: wj = 1..12 — branch-free; unroll 4
    // Body: build(wj) || apply(wj-1) || deferred butterfly+fold(wj-2).
#pragma unroll 4
    for (int wj = 1; wj <= 12; ++wj) {
      P[0][0]=P[0][2]; P[0][1]=P[0][3]; P[0][2]=Q0.x; P[0][3]=Q0.y;
      P[1][0]=P[1][2]; P[1][1]=P[1][3]; P[1][2]=Q1.x; P[1][3]=Q1.y;
      P[2][0]=P[2][2]; P[2][1]=P[2][3]; P[2][2]=Q2.x; P[2][3]=Q2.y;
      P[3][0]=P[3][2]; P[3][1]=P[3][3]; P[3][2]=Q3.x; P[3][3]=Q3.y;
      const int c0n = (wj < 12) ? (2 * wj + 4) : 24;   // clamped: last prefetch unused
      Q0 = *(const float2*)(imgw + 0 * 28 + c0n);
      Q1 = *(const float2*)(imgw + 1 * 28 + c0n);
      Q2 = *(const float2*)(imgw + 2 * 28 + c0n);
      Q3 = *(const float2*)(imgw + 3 * 28 + c0n);
      PICK_FULL;
      build_gate(a0, a1, a2, a3, a4, Wn0, Wn1, Wn2, Wn3);
      APPLY_Z;                                   // window wj-1 -> np
      BF_FOLD;                                   // window wj-2 (or older)
      SHIFT_PEND(wi * 14 + wj - 1);
      ROTATE_W;
    }

    // peel wj = 13: zero-fill slide
#pragma unroll
    for (int r = 0; r < 4; ++r) {
      P[r][0] = P[r][2]; P[r][1] = P[r][3]; P[r][2] = 0.f; P[r][3] = 0.f;
    }
    PICK_W2;
    build_gate(a0, a1, a2, a3, a4, Wn0, Wn1, Wn2, Wn3);
    APPLY_Z;                                     // window 12
    BF_FOLD;                                     // window 11
    SHIFT_PEND(wi * 14 + 12);
    ROTATE_W;
    APPLY_Z;                                     // window 13
    BF_FOLD;                                     // window 12
    SHIFT_PEND(wi * 14 + 13);
  }

  // ================= tail row: wi = 13 (h = 2) =================
  {
    const float* imgw = img + 26 * 28;
#pragma unroll
    for (int r = 0; r < 2; ++r) {
      float4 v = *(const float4*)(imgw + r * 28);
      P[r][0]=v.x; P[r][1]=v.y; P[r][2]=v.z; P[r][3]=v.w;
    }
#pragma unroll
    for (int r = 2; r < 4; ++r) { P[r][0]=0.f; P[r][1]=0.f; P[r][2]=0.f; P[r][3]=0.f; }
    PICK_H2;
    build_gate(a0, a1, a2, a3, a4, Wc0, Wc1, Wc2, Wc3);

    float2 Q0 = *(const float2*)(imgw + 4);
    float2 Q1 = *(const float2*)(imgw + 28 + 4);

#pragma unroll 4
    for (int wj = 1; wj <= 12; ++wj) {
      P[0][0]=P[0][2]; P[0][1]=P[0][3]; P[0][2]=Q0.x; P[0][3]=Q0.y;
      P[1][0]=P[1][2]; P[1][1]=P[1][3]; P[1][2]=Q1.x; P[1][3]=Q1.y;
      const int c0n = (wj < 12) ? (2 * wj + 4) : 24;
      Q0 = *(const float2*)(imgw + c0n);
      Q1 = *(const float2*)(imgw + 28 + c0n);
      PICK_H2;
      build_gate(a0, a1, a2, a3, a4, Wn0, Wn1, Wn2, Wn3);
      APPLY_Z;
      BF_FOLD;
      SHIFT_PEND(182 + wj - 1);
      ROTATE_W;
    }

    P[0][0]=P[0][2]; P[0][1]=P[0][3]; P[0][2]=0.f; P[0][3]=0.f;
    P[1][0]=P[1][2]; P[1][1]=P[1][3]; P[1][2]=0.f; P[1][3]=0.f;
    PICK_22;
    build_gate(a0, a1, a2, a3, a4, Wn0, Wn1, Wn2, Wn3);
    APPLY_Z;                                     // window 194
    BF_FOLD;                                     // window 193
    SHIFT_PEND(182 + 12);
    ROTATE_W;
    APPLY_Z;                                     // window 195
    BF_FOLD;                                     // window 194
    SHIFT_PEND(182 + 13);
  }

  // drain the pipeline: fold window 195
  BF_FOLD;

  // combine the two half-groups' fc1 partials (other 2 features per row)
#pragma unroll
  for (int j = 0; j < 5; ++j) h1[j] += swz4(h1[j]);

  // ---- epilogue: bias + leaky relu + fc2, reduce over quad ----
  float pa = 0.f, pb = 0.f;
#pragma unroll
  for (int j = 0; j < 5; ++j) {
    const int r = 5 * q + j;
    float v = h1[j] + fc1_b[r];
    v = (v > 0.f) ? v : 0.1f * v;
    pa = fmaf(fc2_w[r],      v, pa);
    pb = fmaf(fc2_w[20 + r], v, pb);
  }
  pa += dppf<QP_XOR1>(pa); pa += dppf<QP_XOR2>(pa);
  pb += dppf<QP_XOR1>(pb); pb += dppf<QP_XOR2>(pb);
  if (l8 == 0) {
    float2 res; res.x = pa + fc2_b[0]; res.y = pb + fc2_b[1];
    *(float2*)(out + (size_t)b * 2) = res;
  }
}

extern "C" void kernel_launch(void* const* d_in, const int* in_sizes, int n_in,
                              void* d_out, int out_size, void* d_ws, size_t ws_size,
                              hipStream_t stream) {
  const float* x      = (const float*)d_in[0];
  const float* crz_t  = (const float*)d_in[1];
  const float* ry_t   = (const float*)d_in[2];
  const float* fc1_w  = (const float*)d_in[3];
  const float* fc1_b  = (const float*)d_in[4];
  const float* fc2_w  = (const float*)d_in[5];
  const float* fc2_b  = (const float*)d_in[6];
  float* out = (float*)d_out;
  const int B = in_sizes[0] / 784;
  const int grid = (B * 8 + 255) / 256;
  quanv_kernel<<<grid, 256, 0, stream>>>(x, crz_t, ry_t, fc1_w, fc1_b,
                                         fc2_w, fc2_b, out, B);
}

// Round 2
// 230.562 us; speedup vs baseline: 1.1191x; 1.1191x over previous
//
#include <hip/hip_runtime.h>

#define RS2f 0.70710678118654752f

// DPP quad_perm encodings: sel0 | sel1<<2 | sel2<<4 | sel3<<6
#define QP_XOR1 0xB1   // [1,0,3,2]
#define QP_XOR2 0x4E   // [2,3,0,1]
#define QP_BC0  0x00
#define QP_BC1  0x55
#define QP_BC2  0xAA
#define QP_BC3  0xFF

typedef float v2f __attribute__((ext_vector_type(2)));

template<int CTRL> __device__ __forceinline__ float dppf(float x) {
  return __int_as_float(__builtin_amdgcn_update_dpp(
      0, __float_as_int(x), CTRL, 0xF, 0xF, true));
}
template<int CTRL> __device__ __forceinline__ v2f dpp2(v2f v) {
  v2f r; r.x = dppf<CTRL>(v.x); r.y = dppf<CTRL>(v.y); return r;
}

__device__ __forceinline__ float sxor(float x, int sm) {
  return __int_as_float(__float_as_int(x) ^ sm);
}
__device__ __forceinline__ v2f vsplat(float a) { v2f r; r.x = a; r.y = a; return r; }
__device__ __forceinline__ v2f vperp(v2f v) { v2f r; r.x = -v.y; r.y = v.x; return r; }  //  i*v
__device__ __forceinline__ v2f vperc(v2f v) { v2f r; r.x = v.y; r.y = -v.x; return r; }  // -i*v
__device__ __forceinline__ v2f vfma2(float a, v2f b, v2f c) {
  return __builtin_elementwise_fma(vsplat(a), b, c);
}
__device__ __forceinline__ v2f vmul2(float a, v2f b) { return vsplat(a) * b; }

// Closed-form row0 of U = RZ(a4)RY(a3)RZ(a2)RY(a1)RZ(a0)·H  (verified r8).
__device__ __forceinline__ void build_gate(float a0, float a1, float a2, float a3, float a4,
                                           float &w0r, float &w0i, float &w1r, float &w1i) {
  float sBp, cBp, sBm, cBm, sC, cC, sP, cP, sM, cM;
  __sincosf(0.5f * (a1 + a3), &sBp, &cBp);
  __sincosf(0.5f * (a1 - a3), &sBm, &cBm);
  __sincosf(0.5f * a2,        &sC,  &cC);
  __sincosf(0.5f * (a0 + a4), &sP,  &cP);
  __sincosf(0.5f * (a0 - a4), &sM,  &cM);
  float m00r =  cBp * cC, m00i = -cBm * sC;
  float m01r = -sBp * cC, m01i =  sBm * sC;
  float alr = fmaf(m00r, cP,  m00i * sP);
  float ali = fmaf(m00i, cP, -m00r * sP);
  float ber = fmaf(m01r, cM, -m01i * sM);
  float bei = fmaf(m01i, cM,  m01r * sM);
  w0r = RS2f * (alr + ber); w0i = RS2f * (ali + bei);
  w1r = RS2f * (alr - ber); w1i = RS2f * (ali - bei);
}

#define PICK_FULL                                                            \
  a0 = l0 ? P[0][0] : l1 ? P[1][1] : l2 ? P[2][2] : P[3][3];                 \
  a1 = l0 ? P[0][1] : l1 ? P[1][2] : l2 ? P[2][3] : 0.f;                     \
  a2 = l0 ? P[0][2] : l1 ? P[1][3] : l2 ? P[3][0] : 0.f;                     \
  a3 = l0 ? P[0][3] : l1 ? P[2][0] : l2 ? P[3][1] : 0.f;                     \
  a4 = l0 ? P[1][0] : l1 ? P[2][1] : l2 ? P[3][2] : 0.f;

#define PICK_W2                                                              \
  a0 = l0 ? P[0][0] : l1 ? P[2][1] : 0.f;                                    \
  a1 = l0 ? P[0][1] : l1 ? P[3][0] : 0.f;                                    \
  a2 = l0 ? P[1][0] : l1 ? P[3][1] : 0.f;                                    \
  a3 = l0 ? P[1][1] : 0.f;                                                   \
  a4 = l0 ? P[2][0] : 0.f;

#define PICK_H2                                                              \
  a0 = l0 ? P[0][0] : l1 ? P[1][1] : 0.f;                                    \
  a1 = l0 ? P[0][1] : l1 ? P[1][2] : 0.f;                                    \
  a2 = l0 ? P[0][2] : l1 ? P[1][3] : 0.f;                                    \
  a3 = l0 ? P[0][3] : 0.f;                                                   \
  a4 = l0 ? P[1][0] : 0.f;

#define PICK_22                                                              \
  a0 = l0 ? P[0][0] : 0.f;                                                   \
  a1 = l0 ? P[0][1] : 0.f;                                                   \
  a2 = l0 ? P[1][0] : 0.f;                                                   \
  a3 = l0 ? P[1][1] : 0.f;                                                   \
  a4 = 0.f;

// Apply gate (Wc) to state + CRZ + Ry + Z expectations; emits PRE-butterfly
// per-lane o-values into np0..np3. Verified r8 math, readout split off (r10).
#define APPLY_Z do {                                                         \
  { float w0r = dppf<QP_BC0>(Wc0), w0i = dppf<QP_BC0>(Wc1);                  \
    float w1r = dppf<QP_BC0>(Wc2), w1i = dppf<QP_BC0>(Wc3);                  \
    float uar = sxor(w0r, sm0), uai = w0i;                                   \
    float ubr = w1r,            ubi = sxor(w1i, sm0);                        \
    _Pragma("unroll")                                                        \
    for (int k = 0; k < 4; ++k) {                                            \
      v2f p = dpp2<QP_XOR2>(s[k]);                                           \
      v2f a = s[k];                                                          \
      s[k] = vfma2(uar, a, vfma2(uai, vperp(a),                              \
                   vfma2(ubr, p, vmul2(ubi, vperp(p)))));                    \
    } }                                                                      \
  { float w0r = dppf<QP_BC1>(Wc0), w0i = dppf<QP_BC1>(Wc1);                  \
    float w1r = dppf<QP_BC1>(Wc2), w1i = dppf<QP_BC1>(Wc3);                  \
    float uar = sxor(w0r, sm1), uai = w0i;                                   \
    float ubr = w1r,            ubi = sxor(w1i, sm1);                        \
    _Pragma("unroll")                                                        \
    for (int k = 0; k < 4; ++k) {                                            \
      v2f p = dpp2<QP_XOR1>(s[k]);                                           \
      v2f a = s[k];                                                          \
      s[k] = vfma2(uar, a, vfma2(uai, vperp(a),                              \
                   vfma2(ubr, p, vmul2(ubi, vperp(p)))));                    \
    } }                                                                      \
  { float w0r = dppf<QP_BC2>(Wc0), w0i = dppf<QP_BC2>(Wc1);                  \
    float w1r = dppf<QP_BC2>(Wc2), w1i = dppf<QP_BC2>(Wc3);                  \
    float nw0r = -w0r, nw0i = -w0i;                                          \
    _Pragma("unroll")                                                        \
    for (int k = 0; k < 2; ++k) {                                            \
      v2f lo = s[k], hi = s[k+2];                                            \
      s[k]   = vfma2(w0r, lo, vfma2(w0i, vperp(lo),                          \
                     vfma2(w1r, hi, vmul2(w1i, vperp(hi)))));                \
      s[k+2] = vfma2(w1r, lo, vfma2(w1i, vperc(lo),                          \
                     vfma2(nw0r, hi, vmul2(nw0i, vperc(hi)))));              \
    } }                                                                      \
  { float w0r = dppf<QP_BC3>(Wc0), w0i = dppf<QP_BC3>(Wc1);                  \
    float w1r = dppf<QP_BC3>(Wc2), w1i = dppf<QP_BC3>(Wc3);                  \
    float nw0r = -w0r, nw0i = -w0i;                                          \
    _Pragma("unroll")                                                        \
    for (int k = 0; k < 4; k += 2) {                                         \
      v2f lo = s[k], hi = s[k+1];                                            \
      s[k]   = vfma2(w0r, lo, vfma2(w0i, vperp(lo),                          \
                     vfma2(w1r, hi, vmul2(w1i, vperp(hi)))));                \
      s[k+1] = vfma2(w1r, lo, vfma2(w1i, vperc(lo),                          \
                     vfma2(nw0r, hi, vmul2(nw0i, vperc(hi)))));              \
    } }                                                                      \
  _Pragma("unroll")                                                          \
  for (int k = 0; k < 4; ++k)                                                \
    s[k] = vfma2(czk[k], s[k], vmul2(szk[k], vperp(s[k])));                  \
  _Pragma("unroll")                                                          \
  for (int k = 0; k < 4; ++k) {                                              \
    v2f p = dpp2<QP_XOR2>(s[k]);                                             \
    s[k] = vfma2(cry, s[k], vmul2(sgn0, p));                                 \
  }                                                                          \
  _Pragma("unroll")                                                          \
  for (int k = 0; k < 4; ++k) {                                              \
    v2f p = dpp2<QP_XOR1>(s[k]);                                             \
    s[k] = vfma2(cry, s[k], vmul2(sgn1, p));                                 \
  }                                                                          \
  _Pragma("unroll")                                                          \
  for (int k = 0; k < 2; ++k) {                                              \
    v2f lo = s[k], hi = s[k+2];                                              \
    s[k]   = vfma2(cry, lo, vmul2(nsry, hi));                                \
    s[k+2] = vfma2(sry, lo, vmul2(cry, hi));                                 \
  }                                                                          \
  _Pragma("unroll")                                                          \
  for (int k = 0; k < 4; k += 2) {                                           \
    v2f lo = s[k], hi = s[k+1];                                              \
    s[k]   = vfma2(cry, lo, vmul2(nsry, hi));                                \
    s[k+1] = vfma2(sry, lo, vmul2(cry, hi));                                 \
  }                                                                          \
  { v2f q0 = s[0]*s[0], q1 = s[1]*s[1], q2 = s[2]*s[2], q3 = s[3]*s[3];      \
    float p0 = q0.x + q0.y, p1 = q1.x + q1.y;                                \
    float p2 = q2.x + q2.y, p3 = q3.x + q3.y;                                \
    float s01 = p0 + p1, s23 = p2 + p3;                                      \
    float t_  = s01 + s23;                                                   \
    np0 = sxor(t_, sm0);                                                     \
    np1 = sxor(t_, sm1);                                                     \
    np2 = s01 - s23;                                                         \
    np3 = (p0 - p1) + (p2 - p3);                                             \
  }                                                                          \
} while (0)

// Deferred readout: butterfly + fc1 fold for the PENDING window.
// Weights pw0..pw4 were register-prefetched a FULL window ago (at SHIFT_PEND),
// so no lgkmcnt stall lands here.
#define BF_FOLD do {                                                         \
  float o0 = pd0, o1 = pd1, o2 = pd2, o3 = pd3;                              \
  o0 += dppf<QP_XOR1>(o0); o0 += dppf<QP_XOR2>(o0);                          \
  o1 += dppf<QP_XOR1>(o1); o1 += dppf<QP_XOR2>(o1);                          \
  o2 += dppf<QP_XOR1>(o2); o2 += dppf<QP_XOR2>(o2);                          \
  o3 += dppf<QP_XOR1>(o3); o3 += dppf<QP_XOR2>(o3);                          \
  h1[0] = fmaf(pw0.x, o0, fmaf(pw0.y, o1, fmaf(pw0.z, o2, fmaf(pw0.w, o3, h1[0])))); \
  h1[1] = fmaf(pw1.x, o0, fmaf(pw1.y, o1, fmaf(pw1.z, o2, fmaf(pw1.w, o3, h1[1])))); \
  h1[2] = fmaf(pw2.x, o0, fmaf(pw2.y, o1, fmaf(pw2.z, o2, fmaf(pw2.w, o3, h1[2])))); \
  h1[3] = fmaf(pw3.x, o0, fmaf(pw3.y, o1, fmaf(pw3.z, o2, fmaf(pw3.w, o3, h1[3])))); \
  h1[4] = fmaf(pw4.x, o0, fmaf(pw4.y, o1, fmaf(pw4.z, o2, fmaf(pw4.w, o3, h1[4])))); \
} while (0)

// Shift pending readout AND register-prefetch its fc1 weight columns
// (consumed by BF_FOLD one full window later).
#define SHIFT_PEND(WIN) do {                                                 \
  pd0 = np0; pd1 = np1; pd2 = np2; pd3 = np3;                                \
  const float* wp_ = swl + (WIN) * 4;                                        \
  pw0 = *(const float4*)(wp_);                                               \
  pw1 = *(const float4*)(wp_ + 784);                                         \
  pw2 = *(const float4*)(wp_ + 1568);                                        \
  pw3 = *(const float4*)(wp_ + 2352);                                        \
  pw4 = *(const float4*)(wp_ + 3136);                                        \
} while (0)

#define ROTATE_W  Wc0 = Wn0; Wc1 = Wn1; Wc2 = Wn2; Wc3 = Wn3;

__global__ void __launch_bounds__(256, 1)
quanv_kernel(const float* __restrict__ x,
             const float* __restrict__ crz_t,
             const float* __restrict__ ry_t,
             const float* __restrict__ fc1_w,
             const float* __restrict__ fc1_b,
             const float* __restrict__ fc2_w,
             const float* __restrict__ fc2_b,
             float* __restrict__ out, int B)
{
  __shared__ float sw[20 * 784];
  const int tid = threadIdx.x;
  for (int i = tid; i < (20 * 784) / 4; i += 256)
    ((float4*)sw)[i] = ((const float4*)fc1_w)[i];
  __syncthreads();

  const int l = tid & 3;                       // lane within 4-lane group
  const int b = (blockIdx.x * 256 + tid) >> 2; // element id
  if (b >= B) return;
  const float* img = x + (size_t)b * 784;
  const bool l0 = (l == 0), l1 = (l == 1), l2 = (l == 2);

  // ---- uniform scalar-derived constants ----
  const float theta = crz_t[0];
  const float ryt   = ry_t[0];
  float cry, sry;
  __sincosf(0.5f * ryt, &sry, &cry);
  const float nsry = -sry;
  const float sgn0 = (l & 2) ? sry : -sry;
  const float sgn1 = (l & 1) ? sry : -sry;
  const int sm0 = (l & 2) ? (int)0x80000000 : 0;
  const int sm1 = (l & 1) ? (int)0x80000000 : 0;

  float g0,g1,g2,g3;
  if      (l == 0) { g0= 0.f; g1=-1.f; g2=-1.f; g3=0.f; }
  else if (l == 1) { g0=-1.f; g1=-2.f; g2= 0.f; g3=1.f; }
  else if (l == 2) { g0=-1.f; g1= 0.f; g2=-2.f; g3=1.f; }
  else             { g0= 0.f; g1= 1.f; g2= 1.f; g3=4.f; }
  float czk[4], szk[4];
  __sincosf(0.5f*theta*g0, &szk[0], &czk[0]);
  __sincosf(0.5f*theta*g1, &szk[1], &czk[1]);
  __sincosf(0.5f*theta*g2, &szk[2], &czk[2]);
  __sincosf(0.5f*theta*g3, &szk[3], &czk[3]);

  // state: amp n = 4*l + k; s[k] = (re, im) packed
  v2f s[4];
#pragma unroll
  for (int k = 0; k < 4; ++k) { s[k].x = 0.f; s[k].y = 0.f; }
  if (l == 0) s[0].x = 1.f;

  float h1[5];
#pragma unroll
  for (int j = 0; j < 5; ++j) h1[j] = 0.f;
  const float* swl = sw + 5 * l * 784;

  float P[4][4];
  float a0, a1, a2, a3, a4;
  float Wc0, Wc1, Wc2, Wc3, Wn0, Wn1, Wn2, Wn3;
  float np0, np1, np2, np3;
  float pd0 = 0.f, pd1 = 0.f, pd2 = 0.f, pd3 = 0.f;  // pending readout (0-seeded)
  float4 pw0, pw1, pw2, pw3, pw4;                     // prefetched fc1 weights
  // seed weight prefetch (pd is zero, so any valid weights fold to zero)
  pw0 = *(const float4*)(swl);
  pw1 = *(const float4*)(swl + 784);
  pw2 = *(const float4*)(swl + 1568);
  pw3 = *(const float4*)(swl + 2352);
  pw4 = *(const float4*)(swl + 3136);

  // ================= main rows: wi = 0..12 (h = 4 always) =================
#pragma unroll 1
  for (int wi = 0; wi < 13; ++wi) {
    const float* imgw = img + (2 * wi) * 28;

    // peel wj = 0: fresh load + build only (prev row's pending carries over)
#pragma unroll
    for (int r = 0; r < 4; ++r) {
      float4 v = *(const float4*)(imgw + r * 28);
      P[r][0]=v.x; P[r][1]=v.y; P[r][2]=v.z; P[r][3]=v.w;
    }
    PICK_FULL;
    build_gate(a0, a1, a2, a3, a4, Wc0, Wc1, Wc2, Wc3);

    // prefetch window 1's new columns (cols 4,5)
    float2 Q0 = *(const float2*)(imgw + 0 * 28 + 4);
    float2 Q1 = *(const float2*)(imgw + 1 * 28 + 4);
    float2 Q2 = *(const float2*)(imgw + 2 * 28 + 4);
    float2 Q3 = *(const float2*)(imgw + 3 * 28 + 4);

    // hot loop: wj = 1..12 — branch-free; unroll 4; slide uses prefetched Q,
    // next iteration's Q loads issue here (load-to-use = one full window).
    // Body: build(wj) || apply(wj-1) || deferred butterfly+fold(wj-2).
#pragma unroll 4
    for (int wj = 1; wj <= 12; ++wj) {
      P[0][0]=P[0][2]; P[0][1]=P[0][3]; P[0][2]=Q0.x; P[0][3]=Q0.y;
      P[1][0]=P[1][2]; P[1][1]=P[1][3]; P[1][2]=Q1.x; P[1][3]=Q1.y;
      P[2][0]=P[2][2]; P[2][1]=P[2][3]; P[2][2]=Q2.x; P[2][3]=Q2.y;
      P[3][0]=P[3][2]; P[3][1]=P[3][3]; P[3][2]=Q3.x; P[3][3]=Q3.y;
      const int c0n = (wj < 12) ? (2 * wj + 4) : 24;   // clamped: last prefetch unused
      Q0 = *(const float2*)(imgw + 0 * 28 + c0n);
      Q1 = *(const float2*)(imgw + 1 * 28 + c0n);
      Q2 = *(const float2*)(imgw + 2 * 28 + c0n);
      Q3 = *(const float2*)(imgw + 3 * 28 + c0n);
      PICK_FULL;
      build_gate(a0, a1, a2, a3, a4, Wn0, Wn1, Wn2, Wn3);
      APPLY_Z;                                   // window wj-1 -> np
      BF_FOLD;                                   // window wj-2 (or older)
      SHIFT_PEND(wi * 14 + wj - 1);
      ROTATE_W;
    }

    // peel wj = 13: zero-fill slide
#pragma unroll
    for (int r = 0; r < 4; ++r) {
      P[r][0] = P[r][2]; P[r][1] = P[r][3]; P[r][2] = 0.f; P[r][3] = 0.f;
    }
    PICK_W2;
    build_gate(a0, a1, a2, a3, a4, Wn0, Wn1, Wn2, Wn3);
    APPLY_Z;                                     // window 12
    BF_FOLD;                                     // window 11
    SHIFT_PEND(wi * 14 + 12);
    ROTATE_W;
    APPLY_Z;                                     // window 13
    BF_FOLD;                                     // window 12
    SHIFT_PEND(wi * 14 + 13);
  }

  // ================= tail row: wi = 13 (h = 2) =================
  {
    const float* imgw = img + 26 * 28;
#pragma unroll
    for (int r = 0; r < 2; ++r) {
      float4 v = *(const float4*)(imgw + r * 28);
      P[r][0]=v.x; P[r][1]=v.y; P[r][2]=v.z; P[r][3]=v.w;
    }
#pragma unroll
    for (int r = 2; r < 4; ++r) { P[r][0]=0.f; P[r][1]=0.f; P[r][2]=0.f; P[r][3]=0.f; }
    PICK_H2;
    build_gate(a0, a1, a2, a3, a4, Wc0, Wc1, Wc2, Wc3);

    float2 Q0 = *(const float2*)(imgw + 4);
    float2 Q1 = *(const float2*)(imgw + 28 + 4);

#pragma unroll 4
    for (int wj = 1; wj <= 12; ++wj) {
      P[0][0]=P[0][2]; P[0][1]=P[0][3]; P[0][2]=Q0.x; P[0][3]=Q0.y;
      P[1][0]=P[1][2]; P[1][1]=P[1][3]; P[1][2]=Q1.x; P[1][3]=Q1.y;
      const int c0n = (wj < 12) ? (2 * wj + 4) : 24;
      Q0 = *(const float2*)(imgw + c0n);
      Q1 = *(const float2*)(imgw + 28 + c0n);
      PICK_H2;
      build_gate(a0, a1, a2, a3, a4, Wn0, Wn1, Wn2, Wn3);
      APPLY_Z;
      BF_FOLD;
      SHIFT_PEND(182 + wj - 1);
      ROTATE_W;
    }

    P[0][0]=P[0][2]; P[0][1]=P[0][3]; P[0][2]=0.f; P[0][3]=0.f;
    P[1][0]=P[1][2]; P[1][1]=P[1][3]; P[1][2]=0.f; P[1][3]=0.f;
    PICK_22;
    build_gate(a0, a1, a2, a3, a4, Wn0, Wn1, Wn2, Wn3);
    APPLY_Z;                                     // window 194
    BF_FOLD;                                     // window 193
    SHIFT_PEND(182 + 12);
    ROTATE_W;
    APPLY_Z;                                     // window 195
    BF_FOLD;                                     // window 194
    SHIFT_PEND(182 + 13);
  }

  // drain the pipeline: fold window 195
  BF_FOLD;

  // ---- epilogue: bias + leaky relu + fc2, reduce over group ----
  float pa = 0.f, pb = 0.f;
#pragma unroll
  for (int j = 0; j < 5; ++j) {
    const int r = 5 * l + j;
    float v = h1[j] + fc1_b[r];
    v = (v > 0.f) ? v : 0.1f * v;
    pa = fmaf(fc2_w[r],      v, pa);
    pb = fmaf(fc2_w[20 + r], v, pb);
  }
  pa += dppf<QP_XOR1>(pa); pa += dppf<QP_XOR2>(pa);
  pb += dppf<QP_XOR1>(pb); pb += dppf<QP_XOR2>(pb);
  if (l == 0) {
    float2 res; res.x = pa + fc2_b[0]; res.y = pb + fc2_b[1];
    *(float2*)(out + (size_t)b * 2) = res;
  }
}

extern "C" void kernel_launch(void* const* d_in, const int* in_sizes, int n_in,
                              void* d_out, int out_size, void* d_ws, size_t ws_size,
                              hipStream_t stream) {
  const float* x      = (const float*)d_in[0];
  const float* crz_t  = (const float*)d_in[1];
  const float* ry_t   = (const float*)d_in[2];
  const float* fc1_w  = (const float*)d_in[3];
  const float* fc1_b  = (const float*)d_in[4];
  const float* fc2_w  = (const float*)d_in[5];
  const float* fc2_b  = (const float*)d_in[6];
  float* out = (float*)d_out;
  const int B = in_sizes[0] / 784;
  const int grid = (B * 4 + 255) / 256;
  quanv_kernel<<<grid, 256, 0, stream>>>(x, crz_t, ry_t, fc1_w, fc1_b,
                                         fc2_w, fc2_b, out, B);
}

// Round 3
// 205.491 us; speedup vs baseline: 1.2556x; 1.1220x over previous
//
#include <hip/hip_runtime.h>

#define RS2f 0.70710678118654752f

// DPP quad_perm encodings: sel0 | sel1<<2 | sel2<<4 | sel3<<6
#define QP_XOR1 0xB1   // [1,0,3,2]
#define QP_XOR2 0x4E   // [2,3,0,1]
#define QP_BC0  0x00
#define QP_BC1  0x55
#define QP_BC2  0xAA
#define QP_BC3  0xFF

typedef float v2f __attribute__((ext_vector_type(2)));

template<int CTRL> __device__ __forceinline__ float dppf(float x) {
  return __int_as_float(__builtin_amdgcn_update_dpp(
      0, __float_as_int(x), CTRL, 0xF, 0xF, true));
}
template<int CTRL> __device__ __forceinline__ v2f dpp2(v2f v) {
  v2f r; r.x = dppf<CTRL>(v.x); r.y = dppf<CTRL>(v.y); return r;
}

__device__ __forceinline__ float sxor(float x, int sm) {
  return __int_as_float(__float_as_int(x) ^ sm);
}

// ---- packed-fp32 helpers: complex arithmetic in single VOP3P ops ----
// perp(x) = (-x.y, x.x) = i*x ; perc(x) = (x.y, -x.x) = -i*x
// All perp/perc swaps+negs are folded into op_sel / neg modifiers.

// d = c.lo * x + acc
__device__ __forceinline__ v2f pk_fma_rlo(v2f c, v2f x, v2f acc) {
  v2f d;
  asm("v_pk_fma_f32 %0, %1, %2, %3 op_sel:[0,0,0] op_sel_hi:[0,1,1]"
      : "=v"(d) : "v"(c), "v"(x), "v"(acc));
  return d;
}
// d = -c.lo * x + acc
__device__ __forceinline__ v2f pk_fma_nrlo(v2f c, v2f x, v2f acc) {
  v2f d;
  asm("v_pk_fma_f32 %0, %1, %2, %3 op_sel:[0,0,0] op_sel_hi:[0,1,1] neg_lo:[1,0,0] neg_hi:[1,0,0]"
      : "=v"(d) : "v"(c), "v"(x), "v"(acc));
  return d;
}
// d = c.hi * perp(x) + acc
__device__ __forceinline__ v2f pk_fma_rhip(v2f c, v2f x, v2f acc) {
  v2f d;
  asm("v_pk_fma_f32 %0, %1, %2, %3 op_sel:[1,1,0] op_sel_hi:[1,0,1] neg_lo:[0,1,0]"
      : "=v"(d) : "v"(c), "v"(x), "v"(acc));
  return d;
}
// d = c.hi * perc(x) + acc
__device__ __forceinline__ v2f pk_fma_rhic(v2f c, v2f x, v2f acc) {
  v2f d;
  asm("v_pk_fma_f32 %0, %1, %2, %3 op_sel:[1,1,0] op_sel_hi:[1,0,1] neg_hi:[0,1,0]"
      : "=v"(d) : "v"(c), "v"(x), "v"(acc));
  return d;
}
// d = c.hi * perp(x)
__device__ __forceinline__ v2f pk_mul_rhip(v2f c, v2f x) {
  v2f d;
  asm("v_pk_mul_f32 %0, %1, %2 op_sel:[1,1] op_sel_hi:[1,0] neg_lo:[0,1]"
      : "=v"(d) : "v"(c), "v"(x));
  return d;
}
// d = c.hi * x
__device__ __forceinline__ v2f pk_mul_rhi(v2f c, v2f x) {
  v2f d;
  asm("v_pk_mul_f32 %0, %1, %2 op_sel:[1,0] op_sel_hi:[1,1]"
      : "=v"(d) : "v"(c), "v"(x));
  return d;
}

// native half-angle sincos: s = sin(x/2), c = cos(x/2)
__device__ __forceinline__ void hsc(float x, float* s, float* c) {
  float t = x * 0.07957747154594767f;   // 0.5 / (2*pi), input in revolutions
  *s = __builtin_amdgcn_sinf(t);
  *c = __builtin_amdgcn_cosf(t);
}

// Closed-form row0 of U = RZ(a4)RY(a3)RZ(a2)RY(a1)RZ(a0)·H  (verified r8).
// Output as packed (re,im) pairs: WA = w0, WB = w1.
__device__ __forceinline__ void build_gate(float a0, float a1, float a2, float a3, float a4,
                                           v2f &WA, v2f &WB) {
  float sBp, cBp, sBm, cBm, sC, cC, sP, cP, sM, cM;
  hsc(a1 + a3, &sBp, &cBp);
  hsc(a1 - a3, &sBm, &cBm);
  hsc(a2,      &sC,  &cC);
  hsc(a0 + a4, &sP,  &cP);
  hsc(a0 - a4, &sM,  &cM);
  float m00r =  cBp * cC, m00i = -cBm * sC;
  float m01r = -sBp * cC, m01i =  sBm * sC;
  float alr = fmaf(m00r, cP,  m00i * sP);
  float ali = fmaf(m00i, cP, -m00r * sP);
  float ber = fmaf(m01r, cM, -m01i * sM);
  float bei = fmaf(m01i, cM,  m01r * sM);
  WA.x = RS2f * (alr + ber); WA.y = RS2f * (ali + bei);
  WB.x = RS2f * (alr - ber); WB.y = RS2f * (ali - bei);
}

#define PICK_FULL                                                            \
  a0 = l0 ? P[0][0] : l1 ? P[1][1] : l2 ? P[2][2] : P[3][3];                 \
  a1 = l0 ? P[0][1] : l1 ? P[1][2] : l2 ? P[2][3] : 0.f;                     \
  a2 = l0 ? P[0][2] : l1 ? P[1][3] : l2 ? P[3][0] : 0.f;                     \
  a3 = l0 ? P[0][3] : l1 ? P[2][0] : l2 ? P[3][1] : 0.f;                     \
  a4 = l0 ? P[1][0] : l1 ? P[2][1] : l2 ? P[3][2] : 0.f;

#define PICK_W2                                                              \
  a0 = l0 ? P[0][0] : l1 ? P[2][1] : 0.f;                                    \
  a1 = l0 ? P[0][1] : l1 ? P[3][0] : 0.f;                                    \
  a2 = l0 ? P[1][0] : l1 ? P[3][1] : 0.f;                                    \
  a3 = l0 ? P[1][1] : 0.f;                                                   \
  a4 = l0 ? P[2][0] : 0.f;

#define PICK_H2                                                              \
  a0 = l0 ? P[0][0] : l1 ? P[1][1] : 0.f;                                    \
  a1 = l0 ? P[0][1] : l1 ? P[1][2] : 0.f;                                    \
  a2 = l0 ? P[0][2] : l1 ? P[1][3] : 0.f;                                    \
  a3 = l0 ? P[0][3] : 0.f;                                                   \
  a4 = l0 ? P[1][0] : 0.f;

#define PICK_22                                                              \
  a0 = l0 ? P[0][0] : 0.f;                                                   \
  a1 = l0 ? P[0][1] : 0.f;                                                   \
  a2 = l0 ? P[1][0] : 0.f;                                                   \
  a3 = l0 ? P[1][1] : 0.f;                                                   \
  a4 = 0.f;

// Apply gate (WcA/WcB packed pairs) + CRZ + Ry + Z expectations.
// Identical math to the r0-verified sequence; every complex FMA chain is a
// 4-op v_pk_fma_f32 chain with perp/perc fused into modifiers.
#define APPLY_Z do {                                                         \
  { v2f UA = dpp2<QP_BC0>(WcA), UB = dpp2<QP_BC0>(WcB);                      \
    UA.x = sxor(UA.x, sm0); UB.y = sxor(UB.y, sm0);                          \
    _Pragma("unroll")                                                        \
    for (int k = 0; k < 4; ++k) {                                            \
      v2f p = dpp2<QP_XOR2>(s[k]);                                           \
      v2f a = s[k];                                                          \
      s[k] = pk_fma_rlo(UA, a, pk_fma_rhip(UA, a,                            \
               pk_fma_rlo(UB, p, pk_mul_rhip(UB, p))));                      \
    } }                                                                      \
  { v2f UA = dpp2<QP_BC1>(WcA), UB = dpp2<QP_BC1>(WcB);                      \
    UA.x = sxor(UA.x, sm1); UB.y = sxor(UB.y, sm1);                          \
    _Pragma("unroll")                                                        \
    for (int k = 0; k < 4; ++k) {                                            \
      v2f p = dpp2<QP_XOR1>(s[k]);                                           \
      v2f a = s[k];                                                          \
      s[k] = pk_fma_rlo(UA, a, pk_fma_rhip(UA, a,                            \
               pk_fma_rlo(UB, p, pk_mul_rhip(UB, p))));                      \
    } }                                                                      \
  { v2f W0 = dpp2<QP_BC2>(WcA), W1 = dpp2<QP_BC2>(WcB);                      \
    _Pragma("unroll")                                                        \
    for (int k = 0; k < 2; ++k) {                                            \
      v2f lo = s[k], hi = s[k+2];                                            \
      s[k]   = pk_fma_rlo(W0, lo, pk_fma_rhip(W0, lo,                        \
                 pk_fma_rlo(W1, hi, pk_mul_rhip(W1, hi))));                  \
      s[k+2] = pk_fma_rlo(W1, lo, pk_fma_rhic(W1, lo,                        \
                 pk_fma_nrlo(W0, hi, pk_mul_rhip(W0, hi))));                 \
    } }                                                                      \
  { v2f W0 = dpp2<QP_BC3>(WcA), W1 = dpp2<QP_BC3>(WcB);                      \
    _Pragma("unroll")                                                        \
    for (int k = 0; k < 4; k += 2) {                                         \
      v2f lo = s[k], hi = s[k+1];                                            \
      s[k]   = pk_fma_rlo(W0, lo, pk_fma_rhip(W0, lo,                        \
                 pk_fma_rlo(W1, hi, pk_mul_rhip(W1, hi))));                  \
      s[k+1] = pk_fma_rlo(W1, lo, pk_fma_rhic(W1, lo,                        \
                 pk_fma_nrlo(W0, hi, pk_mul_rhip(W0, hi))));                 \
    } }                                                                      \
  _Pragma("unroll")                                                          \
  for (int k = 0; k < 4; ++k)                                                \
    s[k] = pk_fma_rlo(czv[k], s[k], pk_mul_rhip(czv[k], s[k]));              \
  _Pragma("unroll")                                                          \
  for (int k = 0; k < 4; ++k) {                                              \
    v2f p = dpp2<QP_XOR2>(s[k]);                                             \
    s[k] = pk_fma_rlo(RY0, s[k], pk_mul_rhi(RY0, p));                        \
  }                                                                          \
  _Pragma("unroll")                                                          \
  for (int k = 0; k < 4; ++k) {                                              \
    v2f p = dpp2<QP_XOR1>(s[k]);                                             \
    s[k] = pk_fma_rlo(RY1, s[k], pk_mul_rhi(RY1, p));                        \
  }                                                                          \
  _Pragma("unroll")                                                          \
  for (int k = 0; k < 2; ++k) {                                              \
    v2f lo = s[k], hi = s[k+2];                                              \
    s[k]   = pk_fma_rlo(RA_, lo, pk_mul_rhi(RA_, hi));                       \
    s[k+2] = pk_fma_rlo(RB_, lo, pk_mul_rhi(RB_, hi));                       \
  }                                                                          \
  _Pragma("unroll")                                                          \
  for (int k = 0; k < 4; k += 2) {                                           \
    v2f lo = s[k], hi = s[k+1];                                              \
    s[k]   = pk_fma_rlo(RA_, lo, pk_mul_rhi(RA_, hi));                       \
    s[k+1] = pk_fma_rlo(RB_, lo, pk_mul_rhi(RB_, hi));                       \
  }                                                                          \
  { v2f q0 = s[0]*s[0], q1 = s[1]*s[1], q2 = s[2]*s[2], q3 = s[3]*s[3];      \
    float p0 = q0.x + q0.y, p1 = q1.x + q1.y;                                \
    float p2 = q2.x + q2.y, p3 = q3.x + q3.y;                                \
    float s01 = p0 + p1, s23 = p2 + p3;                                      \
    float t_  = s01 + s23;                                                   \
    np0 = sxor(t_, sm0);                                                     \
    np1 = sxor(t_, sm1);                                                     \
    np2 = s01 - s23;                                                         \
    np3 = (p0 - p1) + (p2 - p3);                                             \
  }                                                                          \
} while (0)

// Deferred readout: butterfly + fc1 fold for the PENDING window (pd*, pdWin).
#define BF_FOLD do {                                                         \
  float o0 = pd0, o1 = pd1, o2 = pd2, o3 = pd3;                              \
  o0 += dppf<QP_XOR1>(o0); o0 += dppf<QP_XOR2>(o0);                          \
  o1 += dppf<QP_XOR1>(o1); o1 += dppf<QP_XOR2>(o1);                          \
  o2 += dppf<QP_XOR1>(o2); o2 += dppf<QP_XOR2>(o2);                          \
  o3 += dppf<QP_XOR1>(o3); o3 += dppf<QP_XOR2>(o3);                          \
  const float* wp = swl + pdWin * 4;                                         \
  float4 wv0 = *(const float4*)(wp);                                         \
  float4 wv1 = *(const float4*)(wp + 784);                                   \
  float4 wv2 = *(const float4*)(wp + 1568);                                  \
  float4 wv3 = *(const float4*)(wp + 2352);                                  \
  float4 wv4 = *(const float4*)(wp + 3136);                                  \
  h1[0] = fmaf(wv0.x, o0, fmaf(wv0.y, o1, fmaf(wv0.z, o2, fmaf(wv0.w, o3, h1[0])))); \
  h1[1] = fmaf(wv1.x, o0, fmaf(wv1.y, o1, fmaf(wv1.z, o2, fmaf(wv1.w, o3, h1[1])))); \
  h1[2] = fmaf(wv2.x, o0, fmaf(wv2.y, o1, fmaf(wv2.z, o2, fmaf(wv2.w, o3, h1[2])))); \
  h1[3] = fmaf(wv3.x, o0, fmaf(wv3.y, o1, fmaf(wv3.z, o2, fmaf(wv3.w, o3, h1[3])))); \
  h1[4] = fmaf(wv4.x, o0, fmaf(wv4.y, o1, fmaf(wv4.z, o2, fmaf(wv4.w, o3, h1[4])))); \
} while (0)

#define SHIFT_PEND(WIN)  pd0 = np0; pd1 = np1; pd2 = np2; pd3 = np3; pdWin = (WIN);
#define ROTATE_W  WcA = WnA; WcB = WnB;

__global__ void __launch_bounds__(256)
quanv_kernel(const float* __restrict__ x,
             const float* __restrict__ crz_t,
             const float* __restrict__ ry_t,
             const float* __restrict__ fc1_w,
             const float* __restrict__ fc1_b,
             const float* __restrict__ fc2_w,
             const float* __restrict__ fc2_b,
             float* __restrict__ out, int B)
{
  __shared__ float sw[20 * 784];
  const int tid = threadIdx.x;
  for (int i = tid; i < (20 * 784) / 4; i += 256)
    ((float4*)sw)[i] = ((const float4*)fc1_w)[i];
  __syncthreads();

  const int l = tid & 3;                       // lane within 4-lane group
  const int b = (blockIdx.x * 256 + tid) >> 2; // element id
  if (b >= B) return;
  const float* img = x + (size_t)b * 784;
  const bool l0 = (l == 0), l1 = (l == 1), l2 = (l == 2);

  // ---- uniform scalar-derived constants ----
  const float theta = crz_t[0];
  const float ryt   = ry_t[0];
  float cry, sry;
  hsc(ryt, &sry, &cry);
  const float sgn0 = (l & 2) ? sry : -sry;
  const float sgn1 = (l & 1) ? sry : -sry;
  const int sm0 = (l & 2) ? (int)0x80000000 : 0;
  const int sm1 = (l & 1) ? (int)0x80000000 : 0;

  v2f RY0, RY1, RA_, RB_;
  RY0.x = cry; RY0.y = sgn0;
  RY1.x = cry; RY1.y = sgn1;
  RA_.x = cry; RA_.y = -sry;
  RB_.x = sry; RB_.y = cry;

  float g0,g1,g2,g3;
  if      (l == 0) { g0= 0.f; g1=-1.f; g2=-1.f; g3=0.f; }
  else if (l == 1) { g0=-1.f; g1=-2.f; g2= 0.f; g3=1.f; }
  else if (l == 2) { g0=-1.f; g1= 0.f; g2=-2.f; g3=1.f; }
  else             { g0= 0.f; g1= 1.f; g2= 1.f; g3=4.f; }
  v2f czv[4];
  { float sz, cz;
    hsc(theta*g0, &sz, &cz); czv[0].x = cz; czv[0].y = sz;
    hsc(theta*g1, &sz, &cz); czv[1].x = cz; czv[1].y = sz;
    hsc(theta*g2, &sz, &cz); czv[2].x = cz; czv[2].y = sz;
    hsc(theta*g3, &sz, &cz); czv[3].x = cz; czv[3].y = sz; }

  // state: amp n = 4*l + k; s[k] = (re, im) packed
  v2f s[4];
#pragma unroll
  for (int k = 0; k < 4; ++k) { s[k].x = 0.f; s[k].y = 0.f; }
  if (l == 0) s[0].x = 1.f;

  float h1[5];
#pragma unroll
  for (int j = 0; j < 5; ++j) h1[j] = 0.f;
  const float* swl = sw + 5 * l * 784;

  float P[4][4];
  float a0, a1, a2, a3, a4;
  v2f WcA, WcB, WnA, WnB;
  float np0, np1, np2, np3;
  float pd0 = 0.f, pd1 = 0.f, pd2 = 0.f, pd3 = 0.f;  // pending readout (0-seeded)
  int pdWin = 0;

  // ================= main rows: wi = 0..12 (h = 4 always) =================
#pragma unroll 1
  for (int wi = 0; wi < 13; ++wi) {
    const float* imgw = img + (2 * wi) * 28;

    // peel wj = 0: fresh load + build only (prev row's pending carries over)
#pragma unroll
    for (int r = 0; r < 4; ++r) {
      float4 v = *(const float4*)(imgw + r * 28);
      P[r][0]=v.x; P[r][1]=v.y; P[r][2]=v.z; P[r][3]=v.w;
    }
    PICK_FULL;
    build_gate(a0, a1, a2, a3, a4, WcA, WcB);

    // prefetch window 1's new columns (cols 4,5)
    float2 Q0 = *(const float2*)(imgw + 0 * 28 + 4);
    float2 Q1 = *(const float2*)(imgw + 1 * 28 + 4);
    float2 Q2 = *(const float2*)(imgw + 2 * 28 + 4);
    float2 Q3 = *(const float2*)(imgw + 3 * 28 + 4);

    // hot loop: wj = 1..12 — branch-free; unroll 2 (natural renaming period).
    // Body: build(wj) || apply(wj-1) || deferred butterfly+fold(wj-2).
#pragma unroll 2
    for (int wj = 1; wj <= 12; ++wj) {
      P[0][0]=P[0][2]; P[0][1]=P[0][3]; P[0][2]=Q0.x; P[0][3]=Q0.y;
      P[1][0]=P[1][2]; P[1][1]=P[1][3]; P[1][2]=Q1.x; P[1][3]=Q1.y;
      P[2][0]=P[2][2]; P[2][1]=P[2][3]; P[2][2]=Q2.x; P[2][3]=Q2.y;
      P[3][0]=P[3][2]; P[3][1]=P[3][3]; P[3][2]=Q3.x; P[3][3]=Q3.y;
      const int c0n = (wj < 12) ? (2 * wj + 4) : 24;   // clamped: last prefetch unused
      Q0 = *(const float2*)(imgw + 0 * 28 + c0n);
      Q1 = *(const float2*)(imgw + 1 * 28 + c0n);
      Q2 = *(const float2*)(imgw + 2 * 28 + c0n);
      Q3 = *(const float2*)(imgw + 3 * 28 + c0n);
      PICK_FULL;
      build_gate(a0, a1, a2, a3, a4, WnA, WnB);
      APPLY_Z;                                   // window wj-1 -> np
      BF_FOLD;                                   // window wj-2 (or older)
      SHIFT_PEND(wi * 14 + wj - 1);
      ROTATE_W;
    }

    // peel wj = 13: zero-fill slide
#pragma unroll
    for (int r = 0; r < 4; ++r) {
      P[r][0] = P[r][2]; P[r][1] = P[r][3]; P[r][2] = 0.f; P[r][3] = 0.f;
    }
    PICK_W2;
    build_gate(a0, a1, a2, a3, a4, WnA, WnB);
    APPLY_Z;                                     // window 12
    BF_FOLD;                                     // window 11
    SHIFT_PEND(wi * 14 + 12);
    ROTATE_W;
    APPLY_Z;                                     // window 13
    BF_FOLD;                                     // window 12
    SHIFT_PEND(wi * 14 + 13);
  }

  // ================= tail row: wi = 13 (h = 2) =================
  {
    const float* imgw = img + 26 * 28;
#pragma unroll
    for (int r = 0; r < 2; ++r) {
      float4 v = *(const float4*)(imgw + r * 28);
      P[r][0]=v.x; P[r][1]=v.y; P[r][2]=v.z; P[r][3]=v.w;
    }
#pragma unroll
    for (int r = 2; r < 4; ++r) { P[r][0]=0.f; P[r][1]=0.f; P[r][2]=0.f; P[r][3]=0.f; }
    PICK_H2;
    build_gate(a0, a1, a2, a3, a4, WcA, WcB);

    float2 Q0 = *(const float2*)(imgw + 4);
    float2 Q1 = *(const float2*)(imgw + 28 + 4);

#pragma unroll 2
    for (int wj = 1; wj <= 12; ++wj) {
      P[0][0]=P[0][2]; P[0][1]=P[0][3]; P[0][2]=Q0.x; P[0][3]=Q0.y;
      P[1][0]=P[1][2]; P[1][1]=P[1][3]; P[1][2]=Q1.x; P[1][3]=Q1.y;
      const int c0n = (wj < 12) ? (2 * wj + 4) : 24;
      Q0 = *(const float2*)(imgw + c0n);
      Q1 = *(const float2*)(imgw + 28 + c0n);
      PICK_H2;
      build_gate(a0, a1, a2, a3, a4, WnA, WnB);
      APPLY_Z;
      BF_FOLD;
      SHIFT_PEND(182 + wj - 1);
      ROTATE_W;
    }

    P[0][0]=P[0][2]; P[0][1]=P[0][3]; P[0][2]=0.f; P[0][3]=0.f;
    P[1][0]=P[1][2]; P[1][1]=P[1][3]; P[1][2]=0.f; P[1][3]=0.f;
    PICK_22;
    build_gate(a0, a1, a2, a3, a4, WnA, WnB);
    APPLY_Z;                                     // window 194
    BF_FOLD;                                     // window 193
    SHIFT_PEND(182 + 12);
    ROTATE_W;
    APPLY_Z;                                     // window 195
    BF_FOLD;                                     // window 194
    SHIFT_PEND(182 + 13);
  }

  // drain the pipeline: fold window 195
  BF_FOLD;

  // ---- epilogue: bias + leaky relu + fc2, reduce over group ----
  float pa = 0.f, pb = 0.f;
#pragma unroll
  for (int j = 0; j < 5; ++j) {
    const int r = 5 * l + j;
    float v = h1[j] + fc1_b[r];
    v = (v > 0.f) ? v : 0.1f * v;
    pa = fmaf(fc2_w[r],      v, pa);
    pb = fmaf(fc2_w[20 + r], v, pb);
  }
  pa += dppf<QP_XOR1>(pa); pa += dppf<QP_XOR2>(pa);
  pb += dppf<QP_XOR1>(pb); pb += dppf<QP_XOR2>(pb);
  if (l == 0) {
    float2 res; res.x = pa + fc2_b[0]; res.y = pb + fc2_b[1];
    *(float2*)(out + (size_t)b * 2) = res;
  }
}

extern "C" void kernel_launch(void* const* d_in, const int* in_sizes, int n_in,
                              void* d_out, int out_size, void* d_ws, size_t ws_size,
                              hipStream_t stream) {
  const float* x      = (const float*)d_in[0];
  const float* crz_t  = (const float*)d_in[1];
  const float* ry_t   = (const float*)d_in[2];
  const float* fc1_w  = (const float*)d_in[3];
  const float* fc1_b  = (const float*)d_in[4];
  const float* fc2_w  = (const float*)d_in[5];
  const float* fc2_b  = (const float*)d_in[6];
  float* out = (float*)d_out;
  const int B = in_sizes[0] / 784;
  const int grid = (B * 4 + 255) / 256;
  quanv_kernel<<<grid, 256, 0, stream>>>(x, crz_t, ry_t, fc1_w, fc1_b,
                                         fc2_w, fc2_b, out, B);
}